// Round 16
// baseline (162.264 us; speedup 1.0000x reference)
//
#include <hip/hip_runtime.h>
#include <hip/hip_bf16.h>
#include <stdint.h>

// Problem constants (from reference)
#define N1 8
#define N2 8
#define PP 1024
#define DD 768
#define PH 32
#define PW 32
#define OH 512
#define OW 512

#define NKT 12   // 768 / 64 K-tiles (BK=64 i8 elements = 64-B rows)

typedef int i32x4 __attribute__((ext_vector_type(4)));

// ---------------- K1: row L2-normalize f32 -> i8 (q = round(127*x/||x||)) --
// Verified R7-R14: final absmax 3.9e-3 vs threshold 1.35e-2.
__global__ __launch_bounds__(256) void nrm_kernel(
    const float* __restrict__ inA, const float* __restrict__ inB,
    char* __restrict__ outA, char* __restrict__ outB) {
  int row = blockIdx.x;
  const float* src;
  char* dst;
  if (row < N1 * PP) {
    src = inA + (size_t)row * DD;
    dst = outA + (size_t)row * DD;
  } else {
    row -= N1 * PP;
    src = inB + (size_t)row * DD;
    dst = outB + (size_t)row * DD;
  }
  const int t = threadIdx.x;
  const float v0 = src[t], v1 = src[t + 256], v2 = src[t + 512];
  float s = v0 * v0 + v1 * v1 + v2 * v2;
#pragma unroll
  for (int m = 32; m; m >>= 1) s += __shfl_xor(s, m, 64);
  __shared__ float red[4];
  const int wave = t >> 6, lane = t & 63;
  if (lane == 0) red[wave] = s;
  __syncthreads();
  const float inv = 127.0f / sqrtf(red[0] + red[1] + red[2] + red[3]);
  dst[t]       = (char)__float2int_rn(v0 * inv);
  dst[t + 256] = (char)__float2int_rn(v1 * inv);
  dst[t + 512] = (char)__float2int_rn(v2 * inv);
}

__device__ __forceinline__ void gll16(const char* src, char* dst) {
  __builtin_amdgcn_global_load_lds(
      (const __attribute__((address_space(1))) void*)src,
      (__attribute__((address_space(3))) void*)dst, 16, 0, 0);
}

// -------- K2: i8 gram row-max, 256x256, BK=64, 4 FAT waves (C=128x128) -----
// R15: REUSE experiment. Evidence R8/R9/R12/R13/R14: every structure moves
// ~128 KB/CU/kt of operand traffic and lands at ~4475 cyc/kt (~29 B/cyc
// delivered), MfmaUtil 19-24%, independent of LDS-vs-L2 path, barriers,
// occupancy, MFMA shape. Lever: cut TRAFFIC. 4 waves (2x2), per-wave C =
// 128x128 -> acc[8][8] i32x4 = 256 VGPRs (1 wave/SIMD, cap ~512, m08: no
// spill through 450). Per wave per kt: a[8]+b[8] = 16 reads; block traffic
// 64 KB reads (vs R8's 96) + 32 KB writes at IDENTICAL MFMA count (256/CU/kt),
// unique bytes, swizzle, and staging math.
// LDS: 2 slots x {A0,A1,B0,B1} x [128 rows][64 B] = 64 KiB. Wave reads only
// A-half wr and B-half wc. Drift sync: stage kt+1 -> 16 ds_read -> 64 MFMA
// -> vmcnt(0) -> ONE barrier (R9-validated; staging has ~3000 cyc to land).
// Swizzle (R7/R8-verified, 0 conflicts): LDS byte y of an 8-KB half holds
// global byte S(y) = y ^ (((y>>7)&7)<<4); read of (row=blk*16+lr, col=lk*16):
// (row*64 + lk*16) ^ (((lr>>1)&7)<<4) (lane-constant XOR; blk*16 ≡ 0 mod 16).
__global__ __launch_bounds__(256, 1) void grami8_kernel(
    const char* __restrict__ fq, const char* __restrict__ gq,
    int* __restrict__ rowmaxI) {
  __shared__ __align__(16) char lds[2][4][8192];  // [slot][A0,A1,B0,B1][.]

  // XCD swizzle: 1024 wgs, 128 contiguous per XCD (bijective, 1024%8==0).
  const int bid = blockIdx.x;
  const int wg = (bid & 7) * 128 + (bid >> 3);
  const int pair = wg >> 4;                 // 0..63
  const int tile = wg & 15;
  const int fn = pair >> 3, gm = pair & 7;
  const int mt = tile >> 2, nt = tile & 3;  // 4x4 tiles of 256x256
  const int brow = mt * 256, bcol = nt * 256;

  const int t = threadIdx.x;
  const int lane = t & 63, wave = t >> 6;
  const int lr = lane & 15, lk = lane >> 4;
  const int wr = wave >> 1, wc = wave & 1;  // 2x2 waves, per-wave C 128x128

  const char* rowA = fq + ((size_t)fn * PP + brow) * DD;
  const char* rowB = gq + ((size_t)gm * PP + bcol) * DD;

  // Staging source mapping (R7/R8-verified 8-KB-half math; 256 threads ->
  // chunks c = t, t+256 per half): x = c*16 ^ (((c>>3)&7)<<4).
  int srow[2], scol[2];
#pragma unroll
  for (int j = 0; j < 2; ++j) {
    const int c = t + j * 256;
    const int x = (c * 16) ^ (((c >> 3) & 7) << 4);
    srow[j] = x >> 6;          // 0..127 local row within half
    scol[j] = x & 63;
  }

  // Fragment read byte offsets within an 8-KB half (R7/R8-verified).
  const int swzv = ((lr >> 1) & 7) << 4;
  const int fbase = (lr * 64 + lk * 16) ^ swzv;  // + blk*1024, blk = 0..7

#define STAGE(rowPtr, h, kt, slotptr)                                      \
  do {                                                                     \
    _Pragma("unroll")                                                      \
    for (int j = 0; j < 2; ++j)                                            \
      gll16(rowPtr + (size_t)((h) * 128 + srow[j]) * DD + (kt) * 64 +      \
                scol[j],                                                   \
            (slotptr) + (t + j * 256) * 16);                               \
  } while (0)

  i32x4 acc[8][8];
#pragma unroll
  for (int i = 0; i < 8; ++i)
#pragma unroll
    for (int j = 0; j < 8; ++j) acc[i][j] = (i32x4){0, 0, 0, 0};

  // Prologue: stage kt 0 into slot 0.
  STAGE(rowB, 0, 0, &lds[0][2][0]);
  STAGE(rowB, 1, 0, &lds[0][3][0]);
  STAGE(rowA, 0, 0, &lds[0][0][0]);
  STAGE(rowA, 1, 0, &lds[0][1][0]);
  asm volatile("s_waitcnt vmcnt(0)" ::: "memory");
  __builtin_amdgcn_s_barrier();
  asm volatile("" ::: "memory");

#pragma unroll 1
  for (int k = 0; k < NKT; ++k) {
    const char* Ab = &lds[k & 1][wr][0];
    const char* Bb = &lds[k & 1][2 + wc][0];

    // Stage kt k+1 into the other slot (readers of it drained before the
    // iter-(k-1) closing barrier; writes land under this iter's MFMA).
    if (k + 1 < NKT) {
      const int ns = (k + 1) & 1;
      STAGE(rowB, 0, k + 1, &lds[ns][2][0]);
      STAGE(rowB, 1, k + 1, &lds[ns][3][0]);
      STAGE(rowA, 0, k + 1, &lds[ns][0][0]);
      STAGE(rowA, 1, k + 1, &lds[ns][1][0]);
    }

    // 16 ds_read_b128 (8 A-frags + 8 B-frags), then 64 MFMA on 64
    // independent accumulators (compiler-graduated lgkmcnt).
    i32x4 a[8], b[8];
#pragma unroll
    for (int m = 0; m < 8; ++m)
      a[m] = *(const i32x4*)(Ab + fbase + m * 1024);
#pragma unroll
    for (int n = 0; n < 8; ++n)
      b[n] = *(const i32x4*)(Bb + fbase + n * 1024);

#pragma unroll
    for (int m = 0; m < 8; ++m)
#pragma unroll
      for (int n = 0; n < 8; ++n)
        acc[m][n] = __builtin_amdgcn_mfma_i32_16x16x64_i8(a[m], b[n],
                                                          acc[m][n], 0, 0, 0);

    // Slot k+1 must be resident before next iter's reads.
    asm volatile("s_waitcnt vmcnt(0)" ::: "memory");
    __builtin_amdgcn_s_barrier();
    asm volatile("" ::: "memory");
  }

  // Row-max epilogue. C/D layout: col = lr, row = lk*4 + reg. Rows of this
  // wave: brow + wr*128 + m*16 + lk*4 + r; two waves (wc=0,1) cover the same
  // rows' two column halves -> combine via global atomicMax (R13: cheap).
  int* rm = rowmaxI + (size_t)(fn * 8 + gm) * PP;
#pragma unroll
  for (int m = 0; m < 8; ++m) {
#pragma unroll
    for (int r = 0; r < 4; ++r) {
      int vv = (int)0x80000000;
#pragma unroll
      for (int n = 0; n < 8; ++n) vv = max(vv, acc[m][n][r]);
      vv = max(vv, __shfl_xor(vv, 1, 64));
      vv = max(vv, __shfl_xor(vv, 2, 64));
      vv = max(vv, __shfl_xor(vv, 4, 64));
      vv = max(vv, __shfl_xor(vv, 8, 64));
      if (lr == 0) {
        const int row = brow + wr * 128 + m * 16 + lk * 4 + r;
        atomicMax(&rm[row], vv);
      }
    }
  }
#undef STAGE
}

// ---------------- K3: rowmax(i32) -> dist -> scores + sp ----------------
__global__ __launch_bounds__(256) void finalize_kernel(
    const int* __restrict__ rowmaxI, float* __restrict__ sp,
    float* __restrict__ scores) {
  const int n = blockIdx.x, t = threadIdx.x;
  const int lane = t & 63, wave = t >> 6;
  __shared__ float red[4];
  __shared__ float maxd[N2];
  float spacc[4] = {0.f, 0.f, 0.f, 0.f};
  for (int m = 0; m < N2; ++m) {
    float lmax = -1e30f;
#pragma unroll
    for (int i = 0; i < 4; ++i) {
      const int p = t + i * 256;
      const float g = (float)rowmaxI[(size_t)(n * N2 + m) * PP + p] *
                      (1.0f / 16129.0f);  // 127^2
      const float d = 0.5f * sqrtf(fmaxf(0.f, 2.f - 2.f * g));
      spacc[i] += d;
      lmax = fmaxf(lmax, d);
    }
#pragma unroll
    for (int msk = 32; msk; msk >>= 1) lmax = fmaxf(lmax, __shfl_xor(lmax, msk, 64));
    if (lane == 0) red[wave] = lmax;
    __syncthreads();
    if (t == 0) maxd[m] = fmaxf(fmaxf(red[0], red[1]), fmaxf(red[2], red[3]));
    __syncthreads();
  }
  if (t == 0) {
    float s = 0.f;
    for (int m = 0; m < N2; ++m) s += maxd[m];
    scores[n] = s * (1.0f / N2);
  }
#pragma unroll
  for (int i = 0; i < 4; ++i)
    sp[(size_t)n * PP + t + i * 256] = spacc[i] * (1.0f / N2);
}

// ---------------- K4: bilinear resize 32x32 -> 512x512 ----------------
__global__ __launch_bounds__(256) void resize_kernel(
    const float* __restrict__ sp, float* __restrict__ out) {
  const int idx = blockIdx.x * 256 + threadIdx.x;
  const int ox = idx & (OW - 1);
  const int oy = (idx >> 9) & (OH - 1);
  const int n = idx >> 18;
  const float sy = (oy + 0.5f) * ((float)PH / OH) - 0.5f;
  const float sx = (ox + 0.5f) * ((float)PW / OW) - 0.5f;
  const float y0f = floorf(sy), x0f = floorf(sx);
  const float wy = sy - y0f, wx = sx - x0f;
  int y0 = (int)y0f, x0 = (int)x0f;
  int y1 = y0 + 1, x1 = x0 + 1;
  y0 = min(max(y0, 0), PH - 1);
  y1 = min(max(y1, 0), PH - 1);
  x0 = min(max(x0, 0), PW - 1);
  x1 = min(max(x1, 0), PW - 1);
  const float* s = sp + (size_t)n * PP;
  const float v00 = s[y0 * PW + x0], v01 = s[y0 * PW + x1];
  const float v10 = s[y1 * PW + x0], v11 = s[y1 * PW + x1];
  const float top = v00 * (1.f - wx) + v01 * wx;
  const float bot = v10 * (1.f - wx) + v11 * wx;
  out[idx] = top * (1.f - wy) + bot * wy;
}

extern "C" void kernel_launch(void* const* d_in, const int* in_sizes, int n_in,
                              void* d_out, int out_size, void* d_ws, size_t ws_size,
                              hipStream_t stream) {
  const float* feats = (const float*)d_in[0];
  const float* nfeats = (const float*)d_in[1];
  float* out = (float*)d_out;

  char* ws = (char*)d_ws;
  const size_t FQ_BYTES = (size_t)N1 * PP * DD;  // 6,291,456
  char* fq = ws;
  char* gq = ws + FQ_BYTES;
  int* rowmaxI = (int*)(ws + 2 * FQ_BYTES);
  float* sp = (float*)(ws + 2 * FQ_BYTES + (size_t)N1 * N2 * PP * 4);

  // rowmax sentinel: 0x80808080 = -2139062144 < -768*127^2 (min possible dot)
  hipMemsetAsync(rowmaxI, 0x80, (size_t)N1 * N2 * PP * 4, stream);

  nrm_kernel<<<(N1 + N2) * PP, 256, 0, stream>>>(feats, nfeats, fq, gq);

  grami8_kernel<<<1024, 256, 0, stream>>>(fq, gq, rowmaxI);

  finalize_kernel<<<N1, 256, 0, stream>>>(rowmaxI, sp, out);
  resize_kernel<<<(N1 * OH * OW) / 256, 256, 0, stream>>>(sp, out + 8);
}

// Round 17
// 128.104 us; speedup vs baseline: 1.2667x; 1.2667x over previous
//
#include <hip/hip_runtime.h>
#include <hip/hip_bf16.h>
#include <stdint.h>

// Problem constants (from reference)
#define N1 8
#define N2 8
#define PP 1024
#define DD 768
#define PH 32
#define PW 32
#define OH 512
#define OW 512

#define NKT 12        // 768 / 64 K-tiles (BK=64)
#define IMG_PK 786432 // packed bytes per image = PP*DD

typedef int i32x4 __attribute__((ext_vector_type(4)));

// ---------------- K1: row L2-normalize f32 -> i8 (q = round(127*x/||x||)) --
// Verified R7-R15: final absmax 3.9e-3 vs threshold 1.35e-2.
__global__ __launch_bounds__(256) void nrm_kernel(
    const float* __restrict__ inA, const float* __restrict__ inB,
    char* __restrict__ outA, char* __restrict__ outB) {
  int row = blockIdx.x;
  const float* src;
  char* dst;
  if (row < N1 * PP) {
    src = inA + (size_t)row * DD;
    dst = outA + (size_t)row * DD;
  } else {
    row -= N1 * PP;
    src = inB + (size_t)row * DD;
    dst = outB + (size_t)row * DD;
  }
  const int t = threadIdx.x;
  const float v0 = src[t], v1 = src[t + 256], v2 = src[t + 512];
  float s = v0 * v0 + v1 * v1 + v2 * v2;
#pragma unroll
  for (int m = 32; m; m >>= 1) s += __shfl_xor(s, m, 64);
  __shared__ float red[4];
  const int wave = t >> 6, lane = t & 63;
  if (lane == 0) red[wave] = s;
  __syncthreads();
  const float inv = 127.0f / sqrtf(red[0] + red[1] + red[2] + red[3]);
  dst[t]       = (char)__float2int_rn(v0 * inv);
  dst[t + 256] = (char)__float2int_rn(v1 * inv);
  dst[t + 512] = (char)__float2int_rn(v2 * inv);
}

// ---------------- K1b: repack g (linear i8) -> fragment-packed i8 ---------
// Packed layout per image (R14-verified): frag unit (blk 0..63, kt 0..11) =
// 1024 B at (blk*12+kt)*1024; byte (lane, e) = element
// (row = blk*16 + (lane&15), col = kt*64 + (lane>>4)*16 + e).
__global__ __launch_bounds__(256) void repackg_kernel(
    const char* __restrict__ gq, char* __restrict__ gpk) {
  const int c = blockIdx.x * 256 + threadIdx.x;  // dest 16-B chunk id
  const int n = c / (IMG_PK / 16);
  const int u = c - n * (IMG_PK / 16);
  const int fu = u >> 6;
  const int ln = u & 63;
  const int blk = fu / NKT, kt = fu - blk * NKT;
  const int row = blk * 16 + (ln & 15);
  const int col = kt * 64 + (ln >> 4) * 16;
  *(i32x4*)(gpk + (size_t)c * 16) =
      *(const i32x4*)(gq + ((size_t)n * PP + row) * DD + col);
}

__device__ __forceinline__ void gll16(const char* src, char* dst) {
  __builtin_amdgcn_global_load_lds(
      (const __attribute__((address_space(1))) void*)src,
      (__attribute__((address_space(3))) void*)dst, 16, 0, 0);
}

// -------- K2: i8 gram row-max, 256x256, BK=64, DUAL-PATH operands ---------
// R16: model-splitting probe. Evidence: every single-pipe structure costs
// ~40 cyc per operand fetch per CU (R8 LDS 41.6, R12 34.8, R13 41.6, R14
// global 53) regardless of barriers/occupancy/shape/iterations. Split the
// operand streams across BOTH pipes:
//  * A-frags (reused by 4 waves) via LDS: 2-slot dbuf x 2 halves x
//    [128 rows][64 B] = 32 KiB; 2 gll16/thread/kt; R7/R8-verified swizzle
//    (0 conflicts). 8 ds_read_b128/wave/kt = 64/CU/kt.
//  * B-frags (reused by 2 waves) straight from fragment-packed GLOBAL
//    (L2-resident 768 KB/pair slice): 4 coalesced 1-KB wave loads/wave/kt
//    = 32/CU/kt. Issued BEFORE the A-staging gll16s so the compiler's
//    b-waits (vmcnt) don't drain the staging FIFO entry.
// If pipes parallelize: per-kt ~ max(64x41.6, 32x53, MFMA 1306) ~ 2700 cyc
// -> gram ~60 us. If per-operand wave constant: unchanged ~89 -> ceiling.
// 8 waves (2M x 4N), per-wave C = 128x64, acc[8][4] i32x4 (R8-verified).
__global__ __launch_bounds__(512, 2) void grami8_kernel(
    const char* __restrict__ fq, const char* __restrict__ gpk,
    int* __restrict__ rowmaxI) {
  __shared__ __align__(16) char Alds[2][2][8192];  // [slot][half][128*64]

  // XCD swizzle: 1024 wgs, 128 contiguous per XCD (bijective, 1024%8==0).
  const int bid = blockIdx.x;
  const int wg = (bid & 7) * 128 + (bid >> 3);
  const int pair = wg >> 4;                 // 0..63
  const int tile = wg & 15;
  const int fn = pair >> 3, gm = pair & 7;
  const int mt = tile >> 2, nt = tile & 3;  // 4x4 tiles of 256x256
  const int brow = mt * 256;

  const int t = threadIdx.x;
  const int lane = t & 63, wave = t >> 6;
  const int lr = lane & 15, lk = lane >> 4;
  const int wr = wave >> 2, wc = wave & 3;  // 2M x 4N, per-wave 128x64

  const char* rowA = fq + ((size_t)fn * PP + brow) * DD;

  // A staging source mapping (R7/R8-verified 8-KB-half math): thread t
  // stages chunk t of half j (j = 0,1): x = t*16 ^ (((t>>3)&7)<<4).
  const int xs = (t * 16) ^ (((t >> 3) & 7) << 4);
  const int srow = xs >> 6;          // 0..127 local row within half
  const int scol = xs & 63;

  // A fragment read offsets within an 8-KB half (R7/R8-verified).
  const int swzv = ((lr >> 1) & 7) << 4;
  const int abase = (lr * 64 + lk * 16) ^ swzv;  // + m*1024

  // B fragment-packed global base: col blocks nt*16 + wc*4 + n.
  const char* Bf = gpk + (size_t)gm * IMG_PK +
                   ((size_t)(nt * 16 + wc * 4) * NKT) * 1024 + lane * 16;

  i32x4 acc[8][4];
#pragma unroll
  for (int i = 0; i < 8; ++i)
#pragma unroll
    for (int j = 0; j < 4; ++j) acc[i][j] = (i32x4){0, 0, 0, 0};

  // Prologue: stage A kt 0 into slot 0.
#pragma unroll
  for (int j = 0; j < 2; ++j)
    gll16(rowA + (size_t)(j * 128 + srow) * DD + scol, &Alds[0][j][t * 16]);
  asm volatile("s_waitcnt vmcnt(0)" ::: "memory");
  __builtin_amdgcn_s_barrier();
  asm volatile("" ::: "memory");

#pragma unroll 1
  for (int k = 0; k < NKT; ++k) {
    const char* Ab = &Alds[k & 1][wr][0];

    // B loads FIRST (ahead of staging in the VMEM FIFO, so the compiler's
    // waits for b[] don't drain the staging entries).
    i32x4 b[4];
#pragma unroll
    for (int n = 0; n < 4; ++n)
      b[n] = *(const i32x4*)(Bf + ((size_t)n * NKT + k) * 1024);

    // Stage A kt k+1 into the other slot (readers drained before the
    // iter-(k-1) closing barrier; writes land under this iter's MFMA).
    if (k + 1 < NKT) {
      const int ns = (k + 1) & 1;
#pragma unroll
      for (int j = 0; j < 2; ++j)
        gll16(rowA + (size_t)(j * 128 + srow) * DD + (k + 1) * 64 + scol,
              &Alds[ns][j][t * 16]);
    }

    // 8 ds_read_b128 (A-frags); compiler-graduated lgkmcnt before MFMAs.
    i32x4 a[8];
#pragma unroll
    for (int m = 0; m < 8; ++m)
      a[m] = *(const i32x4*)(Ab + abase + m * 1024);

#pragma unroll
    for (int m = 0; m < 8; ++m)
#pragma unroll
      for (int n = 0; n < 4; ++n)
        acc[m][n] = __builtin_amdgcn_mfma_i32_16x16x64_i8(a[m], b[n],
                                                          acc[m][n], 0, 0, 0);

    // A slot k+1 must be resident before next iter's reads.
    asm volatile("s_waitcnt vmcnt(0)" ::: "memory");
    __builtin_amdgcn_s_barrier();
    asm volatile("" ::: "memory");
  }

  // Row-max epilogue (R8-verified). C/D layout: col = lr, row = lk*4 + reg.
  int* rm = rowmaxI + (size_t)(fn * 8 + gm) * PP;
#pragma unroll
  for (int m = 0; m < 8; ++m) {
#pragma unroll
    for (int r = 0; r < 4; ++r) {
      int vv = max(max(acc[m][0][r], acc[m][1][r]),
                   max(acc[m][2][r], acc[m][3][r]));
      vv = max(vv, __shfl_xor(vv, 1, 64));
      vv = max(vv, __shfl_xor(vv, 2, 64));
      vv = max(vv, __shfl_xor(vv, 4, 64));
      vv = max(vv, __shfl_xor(vv, 8, 64));
      if (lr == 0) {
        const int row = brow + wr * 128 + m * 16 + lk * 4 + r;
        atomicMax(&rm[row], vv);
      }
    }
  }
}

// ---------------- K3: rowmax(i32) -> dist -> scores + sp ----------------
__global__ __launch_bounds__(256) void finalize_kernel(
    const int* __restrict__ rowmaxI, float* __restrict__ sp,
    float* __restrict__ scores) {
  const int n = blockIdx.x, t = threadIdx.x;
  const int lane = t & 63, wave = t >> 6;
  __shared__ float red[4];
  __shared__ float maxd[N2];
  float spacc[4] = {0.f, 0.f, 0.f, 0.f};
  for (int m = 0; m < N2; ++m) {
    float lmax = -1e30f;
#pragma unroll
    for (int i = 0; i < 4; ++i) {
      const int p = t + i * 256;
      const float g = (float)rowmaxI[(size_t)(n * N2 + m) * PP + p] *
                      (1.0f / 16129.0f);  // 127^2
      const float d = 0.5f * sqrtf(fmaxf(0.f, 2.f - 2.f * g));
      spacc[i] += d;
      lmax = fmaxf(lmax, d);
    }
#pragma unroll
    for (int msk = 32; msk; msk >>= 1) lmax = fmaxf(lmax, __shfl_xor(lmax, msk, 64));
    if (lane == 0) red[wave] = lmax;
    __syncthreads();
    if (t == 0) maxd[m] = fmaxf(fmaxf(red[0], red[1]), fmaxf(red[2], red[3]));
    __syncthreads();
  }
  if (t == 0) {
    float s = 0.f;
    for (int m = 0; m < N2; ++m) s += maxd[m];
    scores[n] = s * (1.0f / N2);
  }
#pragma unroll
  for (int i = 0; i < 4; ++i)
    sp[(size_t)n * PP + t + i * 256] = spacc[i] * (1.0f / N2);
}

// ---------------- K4: bilinear resize 32x32 -> 512x512 ----------------
__global__ __launch_bounds__(256) void resize_kernel(
    const float* __restrict__ sp, float* __restrict__ out) {
  const int idx = blockIdx.x * 256 + threadIdx.x;
  const int ox = idx & (OW - 1);
  const int oy = (idx >> 9) & (OH - 1);
  const int n = idx >> 18;
  const float sy = (oy + 0.5f) * ((float)PH / OH) - 0.5f;
  const float sx = (ox + 0.5f) * ((float)PW / OW) - 0.5f;
  const float y0f = floorf(sy), x0f = floorf(sx);
  const float wy = sy - y0f, wx = sx - x0f;
  int y0 = (int)y0f, x0 = (int)x0f;
  int y1 = y0 + 1, x1 = x0 + 1;
  y0 = min(max(y0, 0), PH - 1);
  y1 = min(max(y1, 0), PH - 1);
  x0 = min(max(x0, 0), PW - 1);
  x1 = min(max(x1, 0), PW - 1);
  const float* s = sp + (size_t)n * PP;
  const float v00 = s[y0 * PW + x0], v01 = s[y0 * PW + x1];
  const float v10 = s[y1 * PW + x0], v11 = s[y1 * PW + x1];
  const float top = v00 * (1.f - wx) + v01 * wx;
  const float bot = v10 * (1.f - wx) + v11 * wx;
  out[idx] = top * (1.f - wy) + bot * wy;
}

extern "C" void kernel_launch(void* const* d_in, const int* in_sizes, int n_in,
                              void* d_out, int out_size, void* d_ws, size_t ws_size,
                              hipStream_t stream) {
  const float* feats = (const float*)d_in[0];
  const float* nfeats = (const float*)d_in[1];
  float* out = (float*)d_out;

  char* ws = (char*)d_ws;
  const size_t FQ_BYTES = (size_t)N1 * PP * DD;  // 6,291,456
  char* fq = ws;
  char* gq = ws + FQ_BYTES;
  char* gpk = ws + 2 * FQ_BYTES;
  int* rowmaxI = (int*)(ws + 3 * FQ_BYTES);
  float* sp = (float*)(ws + 3 * FQ_BYTES + (size_t)N1 * N2 * PP * 4);

  // rowmax sentinel: 0x80808080 = -2139062144 < -768*127^2 (min possible dot)
  hipMemsetAsync(rowmaxI, 0x80, (size_t)N1 * N2 * PP * 4, stream);

  nrm_kernel<<<(N1 + N2) * PP, 256, 0, stream>>>(feats, nfeats, fq, gq);
  repackg_kernel<<<(N2 * IMG_PK / 16) / 256, 256, 0, stream>>>(gq, gpk);

  grami8_kernel<<<1024, 512, 0, stream>>>(fq, gpk, rowmaxI);

  finalize_kernel<<<N1, 256, 0, stream>>>(rowmaxI, sp, out);
  resize_kernel<<<(N1 * OH * OW) / 256, 256, 0, stream>>>(sp, out + 8);
}

// Round 18
// 114.683 us; speedup vs baseline: 1.4149x; 1.1170x over previous
//
#include <hip/hip_runtime.h>
#include <hip/hip_bf16.h>
#include <stdint.h>

// Problem constants (from reference)
#define N1 8
#define N2 8
#define PP 1024
#define DD 768
#define PH 32
#define PW 32
#define OH 512
#define OW 512

#define NKT 6    // 768 / 128 K-tiles (BK=128 i8 elements = 128-B rows)

typedef int i32x4 __attribute__((ext_vector_type(4)));

// ---------------- K1: row L2-normalize f32 -> i8 (q = round(127*x/||x||)) --
// Verified R7-R16: final absmax 3.9e-3 vs threshold 1.35e-2.
__global__ __launch_bounds__(256) void nrm_kernel(
    const float* __restrict__ inA, const float* __restrict__ inB,
    char* __restrict__ outA, char* __restrict__ outB) {
  int row = blockIdx.x;
  const float* src;
  char* dst;
  if (row < N1 * PP) {
    src = inA + (size_t)row * DD;
    dst = outA + (size_t)row * DD;
  } else {
    row -= N1 * PP;
    src = inB + (size_t)row * DD;
    dst = outB + (size_t)row * DD;
  }
  const int t = threadIdx.x;
  const float v0 = src[t], v1 = src[t + 256], v2 = src[t + 512];
  float s = v0 * v0 + v1 * v1 + v2 * v2;
#pragma unroll
  for (int m = 32; m; m >>= 1) s += __shfl_xor(s, m, 64);
  __shared__ float red[4];
  const int wave = t >> 6, lane = t & 63;
  if (lane == 0) red[wave] = s;
  __syncthreads();
  const float inv = 127.0f / sqrtf(red[0] + red[1] + red[2] + red[3]);
  dst[t]       = (char)__float2int_rn(v0 * inv);
  dst[t + 256] = (char)__float2int_rn(v1 * inv);
  dst[t + 512] = (char)__float2int_rn(v2 * inv);
}

__device__ __forceinline__ void gll16(const char* src, char* dst) {
  __builtin_amdgcn_global_load_lds(
      (const __attribute__((address_space(1))) void*)src,
      (__attribute__((address_space(3))) void*)dst, 16, 0, 0);
}

// -------- K2: i8 gram row-max GEMM, 256x256, BK=128, 2-slot drift ----------
// R9-verbatim (best measured: 89.0 us; R8 4-slot: 89.9; all structural
// variants R10-R16 pinned or regressed). Structural envelope note: with
// 8 waves/CU and per-wave acc m*n=32, operand fetch-units/CU/kt64 is
// minimized at 96; measured cost ~40 cyc/fetch across LDS/L2/mixed paths
// (R8/R12/R13/R14/R16) -> per-kt64 ~3840 cyc + MFMA tail ~ observed 4475.
// 8 waves (2M x 4N), per-wave C = 128x64, acc[8][4] i32x4.
// LDS: 2 slots x {A,B} x [256 rows][128 B] = 128 KiB.
// Swizzle (R7/R8/R9-verified, 0 conflicts): LDS byte y of a 32-KB buffer
// holds global byte S(y) = y ^ (((y>>7)&7)<<4); read of (row, col=kk*64+
// lk*16): y = row*128 + ((kk*64 + lk*16) ^ ((row&7)<<4)) (carry-free).
__global__ __launch_bounds__(512, 2) void grami8_kernel(
    const char* __restrict__ fq, const char* __restrict__ gq,
    int* __restrict__ rowmaxI) {
  __shared__ __align__(16) char lds[2][2][32768];  // [slot][A,B][256*128]

  // XCD swizzle: 1024 wgs, 128 contiguous per XCD (bijective, 1024%8==0).
  const int bid = blockIdx.x;
  const int wg = (bid & 7) * 128 + (bid >> 3);
  const int pair = wg >> 4;                 // 0..63
  const int tile = wg & 15;
  const int fn = pair >> 3, gm = pair & 7;
  const int mt = tile >> 2, nt = tile & 3;  // 4x4 tiles of 256x256
  const int brow = mt * 256, bcol = nt * 256;

  const int t = threadIdx.x;
  const int lane = t & 63, wave = t >> 6;
  const int lr = lane & 15, lk = lane >> 4;
  const int wr = wave >> 2, wc = wave & 3;  // 2M x 4N, per-wave 128x64

  const char* rowA = fq + ((size_t)fn * PP + brow) * DD;
  const char* rowB = gq + ((size_t)gm * PP + bcol) * DD;

  // Staging source mapping: chunk c (0..2047) of a 32-KB buffer holds global
  // bytes S(c*16): x = c*16 ^ (((c>>3)&7)<<4); srow = x>>7; scol = x&127.
  int srow[4], scol[4];
#pragma unroll
  for (int j = 0; j < 4; ++j) {
    const int c = t + j * 512;
    const int x = (c * 16) ^ (((c >> 3) & 7) << 4);
    srow[j] = x >> 7;
    scol[j] = x & 127;
  }

  // Fragment read byte offsets.
  const int swzm = (lr & 7) << 4;
  const int fk0 = (0 * 64 + lk * 16) ^ swzm;
  const int fk1 = (1 * 64 + lk * 16) ^ swzm;
  const int abase = (wr * 128 + lr) * 128;          // + m*2048 + fk
  const int bbase = (wc * 64 + lr) * 128;           // + n*2048 + fk

#define STAGE(rowPtr, kt, slot, mat)                                       \
  do {                                                                     \
    _Pragma("unroll")                                                      \
    for (int j = 0; j < 4; ++j)                                            \
      gll16(rowPtr + (size_t)srow[j] * DD + (kt) * 128 + scol[j],          \
            &lds[slot][mat][(t + j * 512) * 16]);                          \
  } while (0)

  i32x4 acc[8][4];
#pragma unroll
  for (int i = 0; i < 8; ++i)
#pragma unroll
    for (int j = 0; j < 4; ++j) acc[i][j] = (i32x4){0, 0, 0, 0};

  // Prologue: stage kt 0 into slot 0.
  STAGE(rowB, 0, 0, 1);
  STAGE(rowA, 0, 0, 0);
  asm volatile("s_waitcnt vmcnt(0)" ::: "memory");
  __builtin_amdgcn_s_barrier();
  asm volatile("" ::: "memory");

#pragma unroll 1
  for (int k = 0; k < NKT; ++k) {
    const char* Ab = &lds[k & 1][0][0];
    const char* Bb = &lds[k & 1][1][0];

    // Stage kt k+1 into the other slot (issue early; lands under MFMA).
    if (k + 1 < NKT) {
      const int ns = (k + 1) & 1;
      STAGE(rowB, k + 1, ns, 1);
      STAGE(rowA, k + 1, ns, 0);
    }

    i32x4 a[8], b[4];
    // ---- K-half 0 (cols 0..63): 12 ds_read_b128 + 32 MFMA ----
#pragma unroll
    for (int m = 0; m < 8; ++m)
      a[m] = *(const i32x4*)(Ab + abase + m * 2048 + fk0);
#pragma unroll
    for (int n = 0; n < 4; ++n)
      b[n] = *(const i32x4*)(Bb + bbase + n * 2048 + fk0);
#pragma unroll
    for (int m = 0; m < 8; ++m)
#pragma unroll
      for (int n = 0; n < 4; ++n)
        acc[m][n] = __builtin_amdgcn_mfma_i32_16x16x64_i8(a[m], b[n],
                                                          acc[m][n], 0, 0, 0);
    // ---- K-half 1 (cols 64..127): 12 ds_read_b128 + 32 MFMA ----
#pragma unroll
    for (int m = 0; m < 8; ++m)
      a[m] = *(const i32x4*)(Ab + abase + m * 2048 + fk1);
#pragma unroll
    for (int n = 0; n < 4; ++n)
      b[n] = *(const i32x4*)(Bb + bbase + n * 2048 + fk1);
#pragma unroll
    for (int m = 0; m < 8; ++m)
#pragma unroll
      for (int n = 0; n < 4; ++n)
        acc[m][n] = __builtin_amdgcn_mfma_i32_16x16x64_i8(a[m], b[n],
                                                          acc[m][n], 0, 0, 0);

    // Slot k+1 must be fully resident before anyone reads it next iter.
    asm volatile("s_waitcnt vmcnt(0)" ::: "memory");
    __builtin_amdgcn_s_barrier();
    asm volatile("" ::: "memory");
  }

  // Row-max epilogue. C/D layout: col = lr, row = lk*4 + reg.
  int* rm = rowmaxI + (size_t)(fn * 8 + gm) * PP;
#pragma unroll
  for (int m = 0; m < 8; ++m) {
#pragma unroll
    for (int r = 0; r < 4; ++r) {
      int vv = max(max(acc[m][0][r], acc[m][1][r]),
                   max(acc[m][2][r], acc[m][3][r]));
      vv = max(vv, __shfl_xor(vv, 1, 64));
      vv = max(vv, __shfl_xor(vv, 2, 64));
      vv = max(vv, __shfl_xor(vv, 4, 64));
      vv = max(vv, __shfl_xor(vv, 8, 64));
      if (lr == 0) {
        const int row = brow + wr * 128 + m * 16 + lk * 4 + r;
        atomicMax(&rm[row], vv);
      }
    }
  }
#undef STAGE
}

// ---------------- K3a: per-(n,m) dist, maxd, sp accumulation --------------
// R17: parallelized finalize — 64 blocks (one per (n,m)) instead of 8 blocks
// looping m serially with per-m barriers. Each block: 1024 p's (4/thread),
// block-reduce max -> maxdG[n*8+m]; atomicAdd d/8 into sp[n][p] (8 adders
// per address; sp pre-zeroed by memsetAsync).
__global__ __launch_bounds__(256) void finalize_kernel(
    const int* __restrict__ rowmaxI, float* __restrict__ sp,
    float* __restrict__ maxdG) {
  const int nm = blockIdx.x;               // n*8 + m
  const int n = nm >> 3;
  const int t = threadIdx.x;
  const int lane = t & 63, wave = t >> 6;
  __shared__ float red[4];
  float lmax = -1e30f;
#pragma unroll
  for (int i = 0; i < 4; ++i) {
    const int p = t + i * 256;
    const float g = (float)rowmaxI[(size_t)nm * PP + p] * (1.0f / 16129.0f);
    const float d = 0.5f * sqrtf(fmaxf(0.f, 2.f - 2.f * g));
    atomicAdd(&sp[(size_t)n * PP + p], d * (1.0f / N2));
    lmax = fmaxf(lmax, d);
  }
#pragma unroll
  for (int msk = 32; msk; msk >>= 1) lmax = fmaxf(lmax, __shfl_xor(lmax, msk, 64));
  if (lane == 0) red[wave] = lmax;
  __syncthreads();
  if (t == 0) maxdG[nm] = fmaxf(fmaxf(red[0], red[1]), fmaxf(red[2], red[3]));
}

// ---------------- K3b: scores[n] = mean_m maxdG[n][m] ----------------------
__global__ __launch_bounds__(64) void scores_kernel(
    const float* __restrict__ maxdG, float* __restrict__ scores) {
  const int t = threadIdx.x;
  if (t < N1) {
    float s = 0.f;
#pragma unroll
    for (int m = 0; m < N2; ++m) s += maxdG[t * N2 + m];
    scores[t] = s * (1.0f / N2);
  }
}

// ---------------- K4: bilinear resize 32x32 -> 512x512 ----------------
__global__ __launch_bounds__(256) void resize_kernel(
    const float* __restrict__ sp, float* __restrict__ out) {
  const int idx = blockIdx.x * 256 + threadIdx.x;
  const int ox = idx & (OW - 1);
  const int oy = (idx >> 9) & (OH - 1);
  const int n = idx >> 18;
  const float sy = (oy + 0.5f) * ((float)PH / OH) - 0.5f;
  const float sx = (ox + 0.5f) * ((float)PW / OW) - 0.5f;
  const float y0f = floorf(sy), x0f = floorf(sx);
  const float wy = sy - y0f, wx = sx - x0f;
  int y0 = (int)y0f, x0 = (int)x0f;
  int y1 = y0 + 1, x1 = x0 + 1;
  y0 = min(max(y0, 0), PH - 1);
  y1 = min(max(y1, 0), PH - 1);
  x0 = min(max(x0, 0), PW - 1);
  x1 = min(max(x1, 0), PW - 1);
  const float* s = sp + (size_t)n * PP;
  const float v00 = s[y0 * PW + x0], v01 = s[y0 * PW + x1];
  const float v10 = s[y1 * PW + x0], v11 = s[y1 * PW + x1];
  const float top = v00 * (1.f - wx) + v01 * wx;
  const float bot = v10 * (1.f - wx) + v11 * wx;
  out[idx] = top * (1.f - wy) + bot * wy;
}

extern "C" void kernel_launch(void* const* d_in, const int* in_sizes, int n_in,
                              void* d_out, int out_size, void* d_ws, size_t ws_size,
                              hipStream_t stream) {
  const float* feats = (const float*)d_in[0];
  const float* nfeats = (const float*)d_in[1];
  float* out = (float*)d_out;

  char* ws = (char*)d_ws;
  const size_t FQ_BYTES = (size_t)N1 * PP * DD;  // 6,291,456
  char* fq = ws;
  char* gq = ws + FQ_BYTES;
  int* rowmaxI = (int*)(ws + 2 * FQ_BYTES);
  float* sp = (float*)(ws + 2 * FQ_BYTES + (size_t)N1 * N2 * PP * 4);
  float* maxdG = (float*)(ws + 2 * FQ_BYTES + (size_t)N1 * N2 * PP * 4 +
                          (size_t)N1 * PP * 4);

  // rowmax sentinel: 0x80808080 = -2139062144 < -768*127^2 (min possible dot)
  hipMemsetAsync(rowmaxI, 0x80, (size_t)N1 * N2 * PP * 4, stream);
  // sp accumulator zeroed (K3a atomicAdds into it every call)
  hipMemsetAsync(sp, 0, (size_t)N1 * PP * 4, stream);

  nrm_kernel<<<(N1 + N2) * PP, 256, 0, stream>>>(feats, nfeats, fq, gq);

  grami8_kernel<<<1024, 512, 0, stream>>>(fq, gq, rowmaxI);

  finalize_kernel<<<N1 * N2, 256, 0, stream>>>(rowmaxI, sp, maxdG);
  scores_kernel<<<1, 64, 0, stream>>>(maxdG, out);
  resize_kernel<<<(N1 * OH * OW) / 256, 256, 0, stream>>>(sp, out + 8);
}

// Round 19
// 111.804 us; speedup vs baseline: 1.4513x; 1.0257x over previous
//
#include <hip/hip_runtime.h>
#include <hip/hip_bf16.h>
#include <stdint.h>

// Problem constants (from reference)
#define N1 8
#define N2 8
#define PP 1024
#define DD 768
#define PH 32
#define PW 32
#define OH 512
#define OW 512

#define NKT 6    // 768 / 128 K-tiles (BK=128 i8 elements = 128-B rows)

typedef int i32x4 __attribute__((ext_vector_type(4)));
typedef float f32x4v __attribute__((ext_vector_type(4)));

// ---------------- K1: row L2-normalize f32 -> i8, ONE WAVE PER ROW --------
// R18: vectorized (Guideline 13). Lane l loads 3x float4 (16 B/lane,
// coalesced 1-KB wave chunks), wave shfl_xor reduce (no LDS/barrier),
// stores 3x char4. q = round(127*x/||x||); verified error budget R7-R17:
// final absmax 3.9e-3 vs threshold 1.35e-2.
__global__ __launch_bounds__(256) void nrm_kernel(
    const float* __restrict__ inA, const float* __restrict__ inB,
    char* __restrict__ outA, char* __restrict__ outB) {
  const int wave = threadIdx.x >> 6, lane = threadIdx.x & 63;
  int row = blockIdx.x * 4 + wave;
  const float* src;
  char* dst;
  if (row < N1 * PP) {
    src = inA + (size_t)row * DD;
    dst = outA + (size_t)row * DD;
  } else {
    row -= N1 * PP;
    src = inB + (size_t)row * DD;
    dst = outB + (size_t)row * DD;
  }
  f32x4v v[3];
#pragma unroll
  for (int j = 0; j < 3; ++j)
    v[j] = *(const f32x4v*)(src + j * 256 + lane * 4);
  float s = 0.f;
#pragma unroll
  for (int j = 0; j < 3; ++j)
#pragma unroll
    for (int e = 0; e < 4; ++e) s += v[j][e] * v[j][e];
#pragma unroll
  for (int m = 32; m; m >>= 1) s += __shfl_xor(s, m, 64);
  const float inv = 127.0f / sqrtf(s);
#pragma unroll
  for (int j = 0; j < 3; ++j) {
    char4 q;
    q.x = (char)__float2int_rn(v[j][0] * inv);
    q.y = (char)__float2int_rn(v[j][1] * inv);
    q.z = (char)__float2int_rn(v[j][2] * inv);
    q.w = (char)__float2int_rn(v[j][3] * inv);
    *(char4*)(dst + j * 256 + lane * 4) = q;
  }
}

__device__ __forceinline__ void gll16(const char* src, char* dst) {
  __builtin_amdgcn_global_load_lds(
      (const __attribute__((address_space(1))) void*)src,
      (__attribute__((address_space(3))) void*)dst, 16, 0, 0);
}

// -------- K2: i8 gram row-max GEMM, 256x256, BK=128, 2-slot drift ----------
// R9-verbatim (best measured: ~88 us). Structural envelope: with 8 waves/CU
// and per-wave acc m*n=32, operand fetch-units/CU/kt64 is minimized at 96;
// measured cost ~40 cyc/fetch across LDS/L2/mixed paths (R8/R12/R13/R14/
// R16) -> per-kt64 ~3840 cyc + tail ~ observed 4475. All structural probes
// (R10-R16) pinned or regressed; lower precision accuracy-blocked.
// 8 waves (2M x 4N), per-wave C = 128x64, acc[8][4] i32x4.
// LDS: 2 slots x {A,B} x [256 rows][128 B] = 128 KiB.
// Swizzle (R7/R8/R9-verified, 0 conflicts): LDS byte y of a 32-KB buffer
// holds global byte S(y) = y ^ (((y>>7)&7)<<4); read of (row, col=kk*64+
// lk*16): y = row*128 + ((kk*64 + lk*16) ^ ((row&7)<<4)) (carry-free).
__global__ __launch_bounds__(512, 2) void grami8_kernel(
    const char* __restrict__ fq, const char* __restrict__ gq,
    int* __restrict__ rowmaxI) {
  __shared__ __align__(16) char lds[2][2][32768];  // [slot][A,B][256*128]

  // XCD swizzle: 1024 wgs, 128 contiguous per XCD (bijective, 1024%8==0).
  const int bid = blockIdx.x;
  const int wg = (bid & 7) * 128 + (bid >> 3);
  const int pair = wg >> 4;                 // 0..63
  const int tile = wg & 15;
  const int fn = pair >> 3, gm = pair & 7;
  const int mt = tile >> 2, nt = tile & 3;  // 4x4 tiles of 256x256
  const int brow = mt * 256, bcol = nt * 256;

  const int t = threadIdx.x;
  const int lane = t & 63, wave = t >> 6;
  const int lr = lane & 15, lk = lane >> 4;
  const int wr = wave >> 2, wc = wave & 3;  // 2M x 4N, per-wave 128x64

  const char* rowA = fq + ((size_t)fn * PP + brow) * DD;
  const char* rowB = gq + ((size_t)gm * PP + bcol) * DD;

  // Staging source mapping: chunk c (0..2047) of a 32-KB buffer holds global
  // bytes S(c*16): x = c*16 ^ (((c>>3)&7)<<4); srow = x>>7; scol = x&127.
  int srow[4], scol[4];
#pragma unroll
  for (int j = 0; j < 4; ++j) {
    const int c = t + j * 512;
    const int x = (c * 16) ^ (((c >> 3) & 7) << 4);
    srow[j] = x >> 7;
    scol[j] = x & 127;
  }

  // Fragment read byte offsets.
  const int swzm = (lr & 7) << 4;
  const int fk0 = (0 * 64 + lk * 16) ^ swzm;
  const int fk1 = (1 * 64 + lk * 16) ^ swzm;
  const int abase = (wr * 128 + lr) * 128;          // + m*2048 + fk
  const int bbase = (wc * 64 + lr) * 128;           // + n*2048 + fk

#define STAGE(rowPtr, kt, slot, mat)                                       \
  do {                                                                     \
    _Pragma("unroll")                                                      \
    for (int j = 0; j < 4; ++j)                                            \
      gll16(rowPtr + (size_t)srow[j] * DD + (kt) * 128 + scol[j],          \
            &lds[slot][mat][(t + j * 512) * 16]);                          \
  } while (0)

  i32x4 acc[8][4];
#pragma unroll
  for (int i = 0; i < 8; ++i)
#pragma unroll
    for (int j = 0; j < 4; ++j) acc[i][j] = (i32x4){0, 0, 0, 0};

  // Prologue: stage kt 0 into slot 0.
  STAGE(rowB, 0, 0, 1);
  STAGE(rowA, 0, 0, 0);
  asm volatile("s_waitcnt vmcnt(0)" ::: "memory");
  __builtin_amdgcn_s_barrier();
  asm volatile("" ::: "memory");

#pragma unroll 1
  for (int k = 0; k < NKT; ++k) {
    const char* Ab = &lds[k & 1][0][0];
    const char* Bb = &lds[k & 1][1][0];

    // Stage kt k+1 into the other slot (issue early; lands under MFMA).
    if (k + 1 < NKT) {
      const int ns = (k + 1) & 1;
      STAGE(rowB, k + 1, ns, 1);
      STAGE(rowA, k + 1, ns, 0);
    }

    i32x4 a[8], b[4];
    // ---- K-half 0 (cols 0..63): 12 ds_read_b128 + 32 MFMA ----
#pragma unroll
    for (int m = 0; m < 8; ++m)
      a[m] = *(const i32x4*)(Ab + abase + m * 2048 + fk0);
#pragma unroll
    for (int n = 0; n < 4; ++n)
      b[n] = *(const i32x4*)(Bb + bbase + n * 2048 + fk0);
#pragma unroll
    for (int m = 0; m < 8; ++m)
#pragma unroll
      for (int n = 0; n < 4; ++n)
        acc[m][n] = __builtin_amdgcn_mfma_i32_16x16x64_i8(a[m], b[n],
                                                          acc[m][n], 0, 0, 0);
    // ---- K-half 1 (cols 64..127): 12 ds_read_b128 + 32 MFMA ----
#pragma unroll
    for (int m = 0; m < 8; ++m)
      a[m] = *(const i32x4*)(Ab + abase + m * 2048 + fk1);
#pragma unroll
    for (int n = 0; n < 4; ++n)
      b[n] = *(const i32x4*)(Bb + bbase + n * 2048 + fk1);
#pragma unroll
    for (int m = 0; m < 8; ++m)
#pragma unroll
      for (int n = 0; n < 4; ++n)
        acc[m][n] = __builtin_amdgcn_mfma_i32_16x16x64_i8(a[m], b[n],
                                                          acc[m][n], 0, 0, 0);

    // Slot k+1 must be fully resident before anyone reads it next iter.
    asm volatile("s_waitcnt vmcnt(0)" ::: "memory");
    __builtin_amdgcn_s_barrier();
    asm volatile("" ::: "memory");
  }

  // Row-max epilogue. C/D layout: col = lr, row = lk*4 + reg.
  int* rm = rowmaxI + (size_t)(fn * 8 + gm) * PP;
#pragma unroll
  for (int m = 0; m < 8; ++m) {
#pragma unroll
    for (int r = 0; r < 4; ++r) {
      int vv = max(max(acc[m][0][r], acc[m][1][r]),
                   max(acc[m][2][r], acc[m][3][r]));
      vv = max(vv, __shfl_xor(vv, 1, 64));
      vv = max(vv, __shfl_xor(vv, 2, 64));
      vv = max(vv, __shfl_xor(vv, 4, 64));
      vv = max(vv, __shfl_xor(vv, 8, 64));
      if (lr == 0) {
        const int row = brow + wr * 128 + m * 16 + lk * 4 + r;
        atomicMax(&rm[row], vv);
      }
    }
  }
#undef STAGE
}

// ---------------- K3: per-(n,m) dist, maxd, sp accumulation --------------
// R17-verified: 64 blocks (one per (n,m)). Each block: 1024 p's (4/thread),
// block-reduce max -> maxdG[nm]; atomicAdd d/8 into sp[n][p] (sp pre-zeroed).
__global__ __launch_bounds__(256) void finalize_kernel(
    const int* __restrict__ rowmaxI, float* __restrict__ sp,
    float* __restrict__ maxdG) {
  const int nm = blockIdx.x;               // n*8 + m
  const int n = nm >> 3;
  const int t = threadIdx.x;
  const int lane = t & 63, wave = t >> 6;
  __shared__ float red[4];
  float lmax = -1e30f;
#pragma unroll
  for (int i = 0; i < 4; ++i) {
    const int p = t + i * 256;
    const float g = (float)rowmaxI[(size_t)nm * PP + p] * (1.0f / 16129.0f);
    const float d = 0.5f * sqrtf(fmaxf(0.f, 2.f - 2.f * g));
    atomicAdd(&sp[(size_t)n * PP + p], d * (1.0f / N2));
    lmax = fmaxf(lmax, d);
  }
#pragma unroll
  for (int msk = 32; msk; msk >>= 1) lmax = fmaxf(lmax, __shfl_xor(lmax, msk, 64));
  if (lane == 0) red[wave] = lmax;
  __syncthreads();
  if (t == 0) maxdG[nm] = fmaxf(fmaxf(red[0], red[1]), fmaxf(red[2], red[3]));
}

// ---------------- K4: bilinear resize + scores (fused) --------------------
// Blocks 0..8191: resize 32x32 -> 512x512. Block 8192: scores[n].
__global__ __launch_bounds__(256) void resize_kernel(
    const float* __restrict__ sp, const float* __restrict__ maxdG,
    float* __restrict__ out) {
  if (blockIdx.x == (N1 * OH * OW) / 256) {
    const int t = threadIdx.x;
    if (t < N1) {
      float s = 0.f;
#pragma unroll
      for (int m = 0; m < N2; ++m) s += maxdG[t * N2 + m];
      out[t] = s * (1.0f / N2);
    }
    return;
  }
  const int idx = blockIdx.x * 256 + threadIdx.x;
  const int ox = idx & (OW - 1);
  const int oy = (idx >> 9) & (OH - 1);
  const int n = idx >> 18;
  const float sy = (oy + 0.5f) * ((float)PH / OH) - 0.5f;
  const float sx = (ox + 0.5f) * ((float)PW / OW) - 0.5f;
  const float y0f = floorf(sy), x0f = floorf(sx);
  const float wy = sy - y0f, wx = sx - x0f;
  int y0 = (int)y0f, x0 = (int)x0f;
  int y1 = y0 + 1, x1 = x0 + 1;
  y0 = min(max(y0, 0), PH - 1);
  y1 = min(max(y1, 0), PH - 1);
  x0 = min(max(x0, 0), PW - 1);
  x1 = min(max(x1, 0), PW - 1);
  const float* s = sp + (size_t)n * PP;
  const float v00 = s[y0 * PW + x0], v01 = s[y0 * PW + x1];
  const float v10 = s[y1 * PW + x0], v11 = s[y1 * PW + x1];
  const float top = v00 * (1.f - wx) + v01 * wx;
  const float bot = v10 * (1.f - wx) + v11 * wx;
  out[8 + idx] = top * (1.f - wy) + bot * wy;
}

extern "C" void kernel_launch(void* const* d_in, const int* in_sizes, int n_in,
                              void* d_out, int out_size, void* d_ws, size_t ws_size,
                              hipStream_t stream) {
  const float* feats = (const float*)d_in[0];
  const float* nfeats = (const float*)d_in[1];
  float* out = (float*)d_out;

  char* ws = (char*)d_ws;
  const size_t FQ_BYTES = (size_t)N1 * PP * DD;  // 6,291,456
  char* fq = ws;
  char* gq = ws + FQ_BYTES;
  int* rowmaxI = (int*)(ws + 2 * FQ_BYTES);
  float* sp = (float*)(ws + 2 * FQ_BYTES + (size_t)N1 * N2 * PP * 4);
  float* maxdG = (float*)(ws + 2 * FQ_BYTES + (size_t)N1 * N2 * PP * 4 +
                          (size_t)N1 * PP * 4);

  // rowmax sentinel: 0x80808080 = -2139062144 < -768*127^2 (min possible dot)
  hipMemsetAsync(rowmaxI, 0x80, (size_t)N1 * N2 * PP * 4, stream);
  // sp accumulator zeroed (K3 atomicAdds into it every call)
  hipMemsetAsync(sp, 0, (size_t)N1 * PP * 4, stream);

  nrm_kernel<<<(N1 + N2) * PP / 4, 256, 0, stream>>>(feats, nfeats, fq, gq);

  grami8_kernel<<<1024, 512, 0, stream>>>(fq, gq, rowmaxI);

  finalize_kernel<<<N1 * N2, 256, 0, stream>>>(rowmaxI, sp, maxdG);
  resize_kernel<<<(N1 * OH * OW) / 256 + 1, 256, 0, stream>>>(sp, maxdG, out);
}